// Round 9
// baseline (1012.238 us; speedup 1.0000x reference)
//
#include <hip/hip_runtime.h>
#include <hip/hip_bf16.h>

#define D 128
typedef unsigned int uint;
typedef unsigned short ushort;
typedef unsigned char uchar;
typedef short short8 __attribute__((ext_vector_type(8)));
typedef float f32x4 __attribute__((ext_vector_type(4)));

#define BKT_SHIFT 8           // 256 dst nodes per bucket
#define NBMAX 512             // max buckets per etype (N <= 131072)
#define PART_EPT 16           // edges per thread in part4_k
#define EPB 4096              // edges per block in part4_k (256*PART_EPT)
#define SCAT_CAP 8192         // LDS CSR staging capacity (ints) per bucket

__device__ __forceinline__ ushort f2bf(float f) {
    uint u = __float_as_uint(f);
    return (ushort)((u + 0x7fffu + ((u >> 16) & 1u)) >> 16);
}
__device__ __forceinline__ float bf2f(uint s) { return __uint_as_float(s << 16); }

// ---------------- cast x (f32) -> xb (bf16), both ntypes ----------------
__global__ __launch_bounds__(256) void cast2_k(const float* __restrict__ A,
                                               const float* __restrict__ B,
                                               ushort* __restrict__ xb, int nd8) {
    int i = blockIdx.x * 256 + threadIdx.x;
    if (i >= 2 * nd8) return;
    const float* src = (i < nd8) ? (A + (size_t)i * 8) : (B + (size_t)(i - nd8) * 8);
    float4 u0 = *(const float4*)src;
    float4 u1 = *(const float4*)(src + 4);
    uint4 pk;
    pk.x = (uint)f2bf(u0.x) | ((uint)f2bf(u0.y) << 16);
    pk.y = (uint)f2bf(u0.z) | ((uint)f2bf(u0.w) << 16);
    pk.z = (uint)f2bf(u1.x) | ((uint)f2bf(u1.y) << 16);
    pk.w = (uint)f2bf(u1.z) | ((uint)f2bf(u1.w) << 16);
    *(uint4*)(xb + (size_t)i * 8) = pk;
}

// ---------------- bucket-granular histogram: LDS privatized ----------------
__global__ __launch_bounds__(256) void bhist4_k(
    const int* __restrict__ s0, const int* __restrict__ d0,
    const int* __restrict__ s1, const int* __restrict__ d1,
    const int* __restrict__ s2, const int* __restrict__ d2,
    const int* __restrict__ s3, const int* __restrict__ d3,
    int* __restrict__ bcs, int* __restrict__ bcd, int N, int E) {
    const int e = blockIdx.y;
    const int* sp = e == 0 ? s0 : e == 1 ? s1 : e == 2 ? s2 : s3;
    const int* dp = e == 0 ? d0 : e == 1 ? d1 : e == 2 ? d2 : d3;
    const int NB = (N + 255) >> BKT_SHIFT;
    __shared__ int hs[NBMAX], hd[NBMAX];
    for (int j = threadIdx.x; j < NBMAX; j += 256) { hs[j] = 0; hd[j] = 0; }
    __syncthreads();
    const int base = blockIdx.x * 8192;
#pragma unroll
    for (int k = 0; k < 8; ++k) {
        int idx = base + (k * 256 + threadIdx.x) * 4;
        if (idx + 4 <= E) {
            int4 s = *(const int4*)(sp + idx);
            int4 d = *(const int4*)(dp + idx);
            atomicAdd(&hs[s.x >> BKT_SHIFT], 1); atomicAdd(&hs[s.y >> BKT_SHIFT], 1);
            atomicAdd(&hs[s.z >> BKT_SHIFT], 1); atomicAdd(&hs[s.w >> BKT_SHIFT], 1);
            atomicAdd(&hd[d.x >> BKT_SHIFT], 1); atomicAdd(&hd[d.y >> BKT_SHIFT], 1);
            atomicAdd(&hd[d.z >> BKT_SHIFT], 1); atomicAdd(&hd[d.w >> BKT_SHIFT], 1);
        } else {
            for (int i = idx; i < E && i < idx + 4; ++i) {
                atomicAdd(&hs[sp[i] >> BKT_SHIFT], 1);
                atomicAdd(&hd[dp[i] >> BKT_SHIFT], 1);
            }
        }
    }
    __syncthreads();
    for (int j = threadIdx.x; j < NB; j += 256) {
        if (hs[j]) atomicAdd(&bcs[e * NBMAX + j], hs[j]);
        if (hd[j]) atomicAdd(&bcd[e * NBMAX + j], hd[j]);
    }
}

// ---------------- exclusive scan over buckets -> bases + cursors ----------------
__global__ __launch_bounds__(512) void bscan_k(
    const int* __restrict__ bcs, const int* __restrict__ bcd,
    int* __restrict__ sbase, int* __restrict__ scur,
    int* __restrict__ dbase, int* __restrict__ dcur, int N) {
    const int e = blockIdx.y;
    const int side = blockIdx.x;
    const int NB = (N + 255) >> BKT_SHIFT;
    const int* in = (side ? bcd : bcs) + e * NBMAX;
    int* b0 = (side ? dbase : sbase) + e * NBMAX;
    int* c0 = (side ? dcur : scur) + e * NBMAX;
    const int tid = threadIdx.x, lane = tid & 63, wid = tid >> 6;
    int v = (tid < NB) ? in[tid] : 0;
    int x = v;
#pragma unroll
    for (int off = 1; off < 64; off <<= 1) {
        int t = __shfl_up(x, off);
        if (lane >= off) x += t;
    }
    __shared__ int ws[8];
    if (lane == 63) ws[wid] = x;
    __syncthreads();
    if (tid == 0) {
        int run = 0;
#pragma unroll
        for (int w = 0; w < 8; ++w) { int t = ws[w]; ws[w] = run; run += t; }
    }
    __syncthreads();
    int excl = ws[wid] + x - v;
    if (tid < NB) { b0[tid] = excl; c0[tid] = excl; }
}

// block-local scan of bucket counts + global range reservation.
__device__ __forceinline__ void scan_reserve(int* h, int* gcur, int* Lb, int* Gb,
                                             int* ws) {
    const int t = threadIdx.x, lane = t & 63, wid = t >> 6;
    int c0 = h[2 * t], c1 = h[2 * t + 1];
    int tsum = c0 + c1;
    int x = tsum;
#pragma unroll
    for (int off = 1; off < 64; off <<= 1) {
        int u = __shfl_up(x, off);
        if (lane >= off) x += u;
    }
    if (lane == 63) ws[wid] = x;
    __syncthreads();
    if (t == 0) {
        int run = 0;
#pragma unroll
        for (int w = 0; w < 4; ++w) { int u = ws[w]; ws[w] = run; run += u; }
    }
    __syncthreads();
    int excl = ws[wid] + x - tsum;
    Lb[2 * t] = excl;
    Lb[2 * t + 1] = excl + c0;
    Gb[2 * t] = c0 ? atomicAdd(&gcur[2 * t], c0) : 0;
    Gb[2 * t + 1] = c1 ? atomicAdd(&gcur[2 * t + 1], c1) : 0;
}

// ---------------- pass 1: bucket-partition with LDS counting-sort ----------------
__global__ __launch_bounds__(256) void part4_k(
    const int* __restrict__ s0, const int* __restrict__ d0,
    const int* __restrict__ s1, const int* __restrict__ d1,
    const int* __restrict__ s2, const int* __restrict__ d2,
    const int* __restrict__ s3, const int* __restrict__ d3,
    int* __restrict__ scur, int* __restrict__ dcur,
    uint* __restrict__ pd, uchar* __restrict__ ps, int N, int E) {
    const int e = blockIdx.y;
    const int* sp = e == 0 ? s0 : e == 1 ? s1 : e == 2 ? s2 : s3;
    const int* dp = e == 0 ? d0 : e == 1 ? d1 : e == 2 ? d2 : d3;
    uint* ptd = pd + (size_t)e * E;
    uchar* pts = ps + (size_t)e * E;
    __shared__ int hd[NBMAX], hs[NBMAX];
    __shared__ int Lb[NBMAX], Gb[NBMAX];
    __shared__ uint rec[EPB];
    __shared__ int dst[EPB];
    __shared__ int ws[4];
    for (int j = threadIdx.x; j < NBMAX; j += 256) { hd[j] = 0; hs[j] = 0; }
    __syncthreads();
    int myd[PART_EPT], mys[PART_EPT], rkd[PART_EPT], rks[PART_EPT];
    const int base = blockIdx.x * EPB;
    const int nE = min(EPB, E - base);
#pragma unroll
    for (int k = 0; k < PART_EPT; ++k) {
        int idx = base + k * 256 + threadIdx.x;
        if (idx < E) {
            int d = dp[idx], s = sp[idx];
            myd[k] = d; mys[k] = s;
            rkd[k] = atomicAdd(&hd[d >> BKT_SHIFT], 1);
            rks[k] = atomicAdd(&hs[s >> BKT_SHIFT], 1);
        } else {
            myd[k] = -1;
        }
    }
    __syncthreads();
    // ---- dst side ----
    scan_reserve(hd, dcur + e * NBMAX, Lb, Gb, ws);
    __syncthreads();
#pragma unroll
    for (int k = 0; k < PART_EPT; ++k) {
        if (myd[k] >= 0) {
            int b = myd[k] >> BKT_SHIFT;
            int q = Lb[b] + rkd[k];
            rec[q] = ((uint)(myd[k] & 255) << 24) | (uint)mys[k];
            dst[q] = Gb[b] + rkd[k];
        }
    }
    __syncthreads();
    for (int i = threadIdx.x; i < nE; i += 256) ptd[dst[i]] = rec[i];
    __syncthreads();
    // ---- src side ----
    scan_reserve(hs, scur + e * NBMAX, Lb, Gb, ws);
    __syncthreads();
#pragma unroll
    for (int k = 0; k < PART_EPT; ++k) {
        if (myd[k] >= 0) {
            int b = mys[k] >> BKT_SHIFT;
            int q = Lb[b] + rks[k];
            rec[q] = (uint)(mys[k] & 255);
            dst[q] = Gb[b] + rks[k];
        }
    }
    __syncthreads();
    for (int i = threadIdx.x; i < nE; i += 256) pts[dst[i]] = (uchar)rec[i];
}

// ---------------- pass 2 (merged): dst scatter -> start/cnt/rs_in/CSR, src count -> rs_out ----------------
__global__ __launch_bounds__(256) void scatsh_k(
    const uint* __restrict__ pd, const int* __restrict__ dbase,
    const int* __restrict__ bcd,
    const uchar* __restrict__ ps, const int* __restrict__ sbase,
    const int* __restrict__ bcs,
    int* __restrict__ start_g, int* __restrict__ cnt_g,
    float* __restrict__ rs_in, float* __restrict__ rs_out,
    int* __restrict__ csr, int N, int E) {
    const int e = blockIdx.y;
    const int b = blockIdx.x;
    const int node0 = b << BKT_SHIFT;
    const int nodes = min(256, N - node0);
    const uint* pt = pd + (size_t)e * E;
    int* out = csr + (size_t)e * E;
    const int csr_base = dbase[e * NBMAX + b];
    const int span = bcd[e * NBMAX + b];
    __shared__ int cnt[256];
    __shared__ int cur[256];
    __shared__ int cs[256];
    __shared__ int woff[4];
    __shared__ int lcsr[SCAT_CAP];
    const int tid = threadIdx.x, lane = tid & 63, wid = tid >> 6;
    cnt[tid] = 0;
    cs[tid] = 0;
    __syncthreads();
    for (int i = tid; i < span; i += 256) atomicAdd(&cnt[pt[csr_base + i] >> 24], 1);
    // src-side count (independent)
    {
        const uchar* pts = ps + (size_t)e * E;
        const int sb = sbase[e * NBMAX + b];
        const int sspan = bcs[e * NBMAX + b];
        for (int i = tid; i < sspan; i += 256) atomicAdd(&cs[pts[sb + i]], 1);
    }
    __syncthreads();
    if (tid < nodes)
        rs_out[(size_t)e * N + node0 + tid] = rsqrtf((float)max(cs[tid], 1));
    int c = cnt[tid];
    int x = c;
#pragma unroll
    for (int off = 1; off < 64; off <<= 1) {
        int t = __shfl_up(x, off);
        if (lane >= off) x += t;
    }
    if (lane == 63) woff[wid] = x;
    __syncthreads();
    if (tid == 0) {
        int run = 0;
#pragma unroll
        for (int w = 0; w < 4; ++w) { int t = woff[w]; woff[w] = run; run += t; }
    }
    __syncthreads();
    int loc = woff[wid] + x - c;
    cur[tid] = loc;
    if (tid < nodes) {
        int n = node0 + tid;
        start_g[(size_t)e * N + n] = csr_base + loc;
        cnt_g[(size_t)e * N + n] = c;
        rs_in[(size_t)e * N + n] = rsqrtf((float)max(c, 1));
    }
    __syncthreads();
    for (int i = tid; i < span; i += 256) {
        uint pk = pt[csr_base + i];
        int pos = atomicAdd(&cur[pk >> 24], 1);
        int s = (int)(pk & 0xFFFFFFu);
        if (pos < SCAT_CAP) lcsr[pos] = s;
        else out[csr_base + pos] = s;  // paranoia guard; statistically unreachable
    }
    __syncthreads();
    const int lim = span < SCAT_CAP ? span : SCAT_CAP;
    for (int i = tid; i < lim; i += 256) out[csr_base + i] = lcsr[i];
}

// ---------------- per-edge weight: csr_rs[e][i] = bf16(rs_out[e][csr[e][i]]) ----------------
// rs_out arrays are 400 KB/etype -> L2-resident gather, csr streamed.
__global__ __launch_bounds__(256) void edgew_k(const int* __restrict__ csr,
                                               const float* __restrict__ rs_out,
                                               ushort* __restrict__ csr_rs, int N, int E) {
    const int e = blockIdx.y;
    const int* c = csr + (size_t)e * E;
    const float* ro = rs_out + (size_t)e * N;
    ushort* w = csr_rs + (size_t)e * E;
    int i = (blockIdx.x * 256 + threadIdx.x) * 4;
    if (i + 4 <= E) {
        int4 s = *(const int4*)(c + i);
        uint2 pk;
        pk.x = (uint)f2bf(ro[s.x]) | ((uint)f2bf(ro[s.y]) << 16);
        pk.y = (uint)f2bf(ro[s.z]) | ((uint)f2bf(ro[s.w]) << 16);
        *(uint2*)(w + i) = pk;
    } else {
        for (; i < E; ++i) w[i] = f2bf(ro[c[i]]);
    }
}

// ---------------- W pre-swizzle into MFMA A-operand (W^T) frag order ----------------
__global__ __launch_bounds__(256) void wswz_k(const float* __restrict__ W0,
                                              const float* __restrict__ W1,
                                              ushort* __restrict__ WF) {
    int t = blockIdx.x * 256 + threadIdx.x;  // 16384 threads total
    int lane = t & 63, kf = (t >> 6) & 3, ct = (t >> 8) & 7, e = (t >> 11) & 3, l = (t >> 13) & 1;
    const float* Ws = (l ? W1 : W0) + (size_t)e * D * D;
    int m = lane & 15, q = lane >> 4;
    const float* src = Ws + (size_t)(kf * 32 + q * 8) * D + ct * 16 + m;
    ushort v[8];
#pragma unroll
    for (int j = 0; j < 8; ++j) v[j] = f2bf(src[(size_t)j * D]);
    uint4 pk;
    pk.x = (uint)v[0] | ((uint)v[1] << 16);
    pk.y = (uint)v[2] | ((uint)v[3] << 16);
    pk.z = (uint)v[4] | ((uint)v[5] << 16);
    pk.w = (uint)v[6] | ((uint)v[7] << 16);
    *(uint4*)(WF + ((size_t)(l * 4 + e) * 2048 + (ct * 4 + kf) * 64 + lane) * 8) = pk;
}

// ---------------- aggregate-first: agg_e[d] = rs_in_e[d] * sum xb_s * rs_out_e[s] ----------------
// Gathers from the 2 shared xb arrays (51 MB resident vs 102 MB for per-etype y).
// Per-edge weight streamed from csr_rs (wave-uniform scalar loads).
__global__ __launch_bounds__(256) void agg4v2_k(
    const ushort* __restrict__ xin, const int* __restrict__ csr,
    const ushort* __restrict__ csr_rs,
    const int* __restrict__ start, const int* __restrict__ cnt,
    const float* __restrict__ rs_in,
    ushort* __restrict__ agg, int N, int E) {
    const int dt = blockIdx.y;
    const int eA = dt, eB = dt + 2;   // eA: src ntype A, eB: src ntype B
    const int lane = threadIdx.x & 63;
    const int row = blockIdx.x * 4 + (threadIdx.x >> 6);
    if (row >= N) return;
    const size_t nd = (size_t)N * D;
    const uint* XA = (const uint*)xin;
    const uint* XB = (const uint*)(xin + nd);
    const int* cAp = csr + (size_t)eA * E;
    const int* cBp = csr + (size_t)eB * E;
    const ushort* wAp = csr_rs + (size_t)eA * E;
    const ushort* wBp = csr_rs + (size_t)eB * E;
    int iA = start[(size_t)eA * N + row], enA = iA + cnt[(size_t)eA * N + row];
    int iB = start[(size_t)eB * N + row], enB = iB + cnt[(size_t)eB * N + row];
    float a0 = 0.f, a1 = 0.f, c0 = 0.f, c1 = 0.f;
    while (iA + 4 <= enA && iB + 4 <= enB) {
        int sa0 = cAp[iA], sa1 = cAp[iA + 1], sa2 = cAp[iA + 2], sa3 = cAp[iA + 3];
        int sb0 = cBp[iB], sb1 = cBp[iB + 1], sb2 = cBp[iB + 2], sb3 = cBp[iB + 3];
        float wa0 = bf2f(wAp[iA]), wa1 = bf2f(wAp[iA + 1]);
        float wa2 = bf2f(wAp[iA + 2]), wa3 = bf2f(wAp[iA + 3]);
        float wb0 = bf2f(wBp[iB]), wb1 = bf2f(wBp[iB + 1]);
        float wb2 = bf2f(wBp[iB + 2]), wb3 = bf2f(wBp[iB + 3]);
        uint pa0 = XA[(size_t)sa0 * 64 + lane], pa1 = XA[(size_t)sa1 * 64 + lane];
        uint pa2 = XA[(size_t)sa2 * 64 + lane], pa3 = XA[(size_t)sa3 * 64 + lane];
        uint pb0 = XB[(size_t)sb0 * 64 + lane], pb1 = XB[(size_t)sb1 * 64 + lane];
        uint pb2 = XB[(size_t)sb2 * 64 + lane], pb3 = XB[(size_t)sb3 * 64 + lane];
        a0 = fmaf(bf2f(pa0 & 0xffffu), wa0, a0); a1 = fmaf(bf2f(pa0 >> 16), wa0, a1);
        a0 = fmaf(bf2f(pa1 & 0xffffu), wa1, a0); a1 = fmaf(bf2f(pa1 >> 16), wa1, a1);
        a0 = fmaf(bf2f(pa2 & 0xffffu), wa2, a0); a1 = fmaf(bf2f(pa2 >> 16), wa2, a1);
        a0 = fmaf(bf2f(pa3 & 0xffffu), wa3, a0); a1 = fmaf(bf2f(pa3 >> 16), wa3, a1);
        c0 = fmaf(bf2f(pb0 & 0xffffu), wb0, c0); c1 = fmaf(bf2f(pb0 >> 16), wb0, c1);
        c0 = fmaf(bf2f(pb1 & 0xffffu), wb1, c0); c1 = fmaf(bf2f(pb1 >> 16), wb1, c1);
        c0 = fmaf(bf2f(pb2 & 0xffffu), wb2, c0); c1 = fmaf(bf2f(pb2 >> 16), wb2, c1);
        c0 = fmaf(bf2f(pb3 & 0xffffu), wb3, c0); c1 = fmaf(bf2f(pb3 >> 16), wb3, c1);
        iA += 4; iB += 4;
    }
    for (; iA + 4 <= enA; iA += 4) {
        int s0 = cAp[iA], s1 = cAp[iA + 1], s2 = cAp[iA + 2], s3 = cAp[iA + 3];
        float w0 = bf2f(wAp[iA]), w1 = bf2f(wAp[iA + 1]);
        float w2 = bf2f(wAp[iA + 2]), w3 = bf2f(wAp[iA + 3]);
        uint p0 = XA[(size_t)s0 * 64 + lane], p1 = XA[(size_t)s1 * 64 + lane];
        uint p2 = XA[(size_t)s2 * 64 + lane], p3 = XA[(size_t)s3 * 64 + lane];
        a0 = fmaf(bf2f(p0 & 0xffffu), w0, a0); a1 = fmaf(bf2f(p0 >> 16), w0, a1);
        a0 = fmaf(bf2f(p1 & 0xffffu), w1, a0); a1 = fmaf(bf2f(p1 >> 16), w1, a1);
        a0 = fmaf(bf2f(p2 & 0xffffu), w2, a0); a1 = fmaf(bf2f(p2 >> 16), w2, a1);
        a0 = fmaf(bf2f(p3 & 0xffffu), w3, a0); a1 = fmaf(bf2f(p3 >> 16), w3, a1);
    }
    for (; iB + 4 <= enB; iB += 4) {
        int s0 = cBp[iB], s1 = cBp[iB + 1], s2 = cBp[iB + 2], s3 = cBp[iB + 3];
        float w0 = bf2f(wBp[iB]), w1 = bf2f(wBp[iB + 1]);
        float w2 = bf2f(wBp[iB + 2]), w3 = bf2f(wBp[iB + 3]);
        uint p0 = XB[(size_t)s0 * 64 + lane], p1 = XB[(size_t)s1 * 64 + lane];
        uint p2 = XB[(size_t)s2 * 64 + lane], p3 = XB[(size_t)s3 * 64 + lane];
        c0 = fmaf(bf2f(p0 & 0xffffu), w0, c0); c1 = fmaf(bf2f(p0 >> 16), w0, c1);
        c0 = fmaf(bf2f(p1 & 0xffffu), w1, c0); c1 = fmaf(bf2f(p1 >> 16), w1, c1);
        c0 = fmaf(bf2f(p2 & 0xffffu), w2, c0); c1 = fmaf(bf2f(p2 >> 16), w2, c1);
        c0 = fmaf(bf2f(p3 & 0xffffu), w3, c0); c1 = fmaf(bf2f(p3 >> 16), w3, c1);
    }
    for (; iA < enA; ++iA) {
        float w = bf2f(wAp[iA]);
        uint p = XA[(size_t)cAp[iA] * 64 + lane];
        a0 = fmaf(bf2f(p & 0xffffu), w, a0); a1 = fmaf(bf2f(p >> 16), w, a1);
    }
    for (; iB < enB; ++iB) {
        float w = bf2f(wBp[iB]);
        uint p = XB[(size_t)cBp[iB] * 64 + lane];
        c0 = fmaf(bf2f(p & 0xffffu), w, c0); c1 = fmaf(bf2f(p >> 16), w, c1);
    }
    float riA = rs_in[(size_t)eA * N + row], riB = rs_in[(size_t)eB * N + row];
    uint* AG = (uint*)agg;
    AG[((size_t)eA * N + row) * 64 + lane] =
        (uint)f2bf(a0 * riA) | ((uint)f2bf(a1 * riA) << 16);
    AG[((size_t)eB * N + row) * 64 + lane] =
        (uint)f2bf(c0 * riB) | ((uint)f2bf(c1 * riB) << 16);
}

// ---------------- GEMM + bias + relu + relation-sum + LayerNorm ----------------
// blockIdx.y = dst ntype p; relations e0=p, e1=p+2. layer0 writes bf16 xb_out;
// layer1 writes f32 outA/outB. (Verified correct in R4 run.)
__global__ __launch_bounds__(256) void gemm_ln_k(
    const ushort* __restrict__ AGG, const ushort* __restrict__ WF,
    const float* __restrict__ bias, const float* __restrict__ lng,
    const float* __restrict__ lnb, ushort* __restrict__ xb_out,
    float* __restrict__ outA, float* __restrict__ outB,
    int n, int layer, int act) {
    const int p = blockIdx.y;
    const int e0 = p, e1 = p + 2;
    const short8* F0 = (const short8*)(WF + (size_t)e0 * 16384);
    const short8* F1 = (const short8*)(WF + (size_t)e1 * 16384);
    const ushort* A0 = AGG + (size_t)e0 * n * D;
    const ushort* A1 = AGG + (size_t)e1 * n * D;
    const int lane = threadIdx.x & 63;
    const int m = lane & 15, q = lane >> 4;
    const int wave = blockIdx.x * 4 + (threadIdx.x >> 6);
    const int nw = gridDim.x * 4;
    const int nstrips = (n + 15) >> 4;
    for (int sidx = wave; sidx < nstrips; sidx += nw) {
        const int r = sidx * 16 + m;
        const int rc = r < n ? r : n - 1;
        const ushort* xpA = A0 + (size_t)rc * D + q * 8;
        const ushort* xpB = A1 + (size_t)rc * D + q * 8;
        short8 xa[4], xv[4];
#pragma unroll
        for (int kf = 0; kf < 4; ++kf) {
            xa[kf] = *(const short8*)(xpA + kf * 32);
            xv[kf] = *(const short8*)(xpB + kf * 32);
        }
        f32x4 a0[8], a1[8];
#pragma unroll
        for (int ct = 0; ct < 8; ++ct) {
            a0[ct] = (f32x4){0.f, 0.f, 0.f, 0.f};
            a1[ct] = (f32x4){0.f, 0.f, 0.f, 0.f};
        }
#pragma unroll
        for (int ct = 0; ct < 8; ++ct)
#pragma unroll
            for (int kf = 0; kf < 4; ++kf) {
                a0[ct] = __builtin_amdgcn_mfma_f32_16x16x32_bf16(
                    F0[(ct * 4 + kf) * 64 + lane], xa[kf], a0[ct], 0, 0, 0);
                a1[ct] = __builtin_amdgcn_mfma_f32_16x16x32_bf16(
                    F1[(ct * 4 + kf) * 64 + lane], xv[kf], a1[ct], 0, 0, 0);
            }
        if (r < n) {
            float s = 0.f, qq = 0.f;
#pragma unroll
            for (int ct = 0; ct < 8; ++ct) {
                float4 bA = *(const float4*)(bias + e0 * D + ct * 16 + q * 4);
                float4 bB = *(const float4*)(bias + e1 * D + ct * 16 + q * 4);
                float x0 = a0[ct][0] + bA.x, w0 = a1[ct][0] + bB.x;
                float x1 = a0[ct][1] + bA.y, w1 = a1[ct][1] + bB.y;
                float x2 = a0[ct][2] + bA.z, w2 = a1[ct][2] + bB.z;
                float x3 = a0[ct][3] + bA.w, w3 = a1[ct][3] + bB.w;
                if (act) {
                    x0 = fmaxf(x0, 0.f); x1 = fmaxf(x1, 0.f);
                    x2 = fmaxf(x2, 0.f); x3 = fmaxf(x3, 0.f);
                    w0 = fmaxf(w0, 0.f); w1 = fmaxf(w1, 0.f);
                    w2 = fmaxf(w2, 0.f); w3 = fmaxf(w3, 0.f);
                }
                float v0 = x0 + w0, v1 = x1 + w1, v2 = x2 + w2, v3 = x3 + w3;
                a0[ct][0] = v0; a0[ct][1] = v1; a0[ct][2] = v2; a0[ct][3] = v3;
                s += v0 + v1 + v2 + v3;
                qq += v0 * v0 + v1 * v1 + v2 * v2 + v3 * v3;
            }
            s += __shfl_xor(s, 16); s += __shfl_xor(s, 32);
            qq += __shfl_xor(qq, 16); qq += __shfl_xor(qq, 32);
            float mean = s * (1.f / 128.f);
            float var = qq * (1.f / 128.f) - mean * mean;
            float inv = rsqrtf(var + 1e-5f);
            const int gbase = (layer * 2 + p) * D;
            if (layer == 0) {
                ushort* yr = xb_out + (size_t)p * n * D + (size_t)r * D + q * 4;
#pragma unroll
                for (int ct = 0; ct < 8; ++ct) {
                    float4 g = *(const float4*)(lng + gbase + ct * 16 + q * 4);
                    float4 be = *(const float4*)(lnb + gbase + ct * 16 + q * 4);
                    float o0 = fmaf((a0[ct][0] - mean) * inv, g.x, be.x);
                    float o1 = fmaf((a0[ct][1] - mean) * inv, g.y, be.y);
                    float o2 = fmaf((a0[ct][2] - mean) * inv, g.z, be.z);
                    float o3 = fmaf((a0[ct][3] - mean) * inv, g.w, be.w);
                    uint2 wv;
                    wv.x = (uint)f2bf(o0) | ((uint)f2bf(o1) << 16);
                    wv.y = (uint)f2bf(o2) | ((uint)f2bf(o3) << 16);
                    *(uint2*)(yr + ct * 16) = wv;
                }
            } else {
                float* OUT = (p ? outB : outA) + (size_t)r * D + q * 4;
#pragma unroll
                for (int ct = 0; ct < 8; ++ct) {
                    float4 g = *(const float4*)(lng + gbase + ct * 16 + q * 4);
                    float4 be = *(const float4*)(lnb + gbase + ct * 16 + q * 4);
                    float4 o;
                    o.x = fmaf((a0[ct][0] - mean) * inv, g.x, be.x);
                    o.y = fmaf((a0[ct][1] - mean) * inv, g.y, be.y);
                    o.z = fmaf((a0[ct][2] - mean) * inv, g.z, be.z);
                    o.w = fmaf((a0[ct][3] - mean) * inv, g.w, be.w);
                    *(float4*)(OUT + ct * 16) = o;
                }
            }
        }
    }
}

extern "C" void kernel_launch(void* const* d_in, const int* in_sizes, int n_in,
                              void* d_out, int out_size, void* d_ws, size_t ws_size,
                              hipStream_t stream) {
    const int N = in_sizes[0] / D;
    const int E = in_sizes[8];
    const float* xA = (const float*)d_in[0];
    const float* xB = (const float*)d_in[1];
    const float* W0 = (const float*)d_in[2];
    const float* b0 = (const float*)d_in[3];
    const float* W1 = (const float*)d_in[4];
    const float* b1 = (const float*)d_in[5];
    const float* lng = (const float*)d_in[6];
    const float* lnb = (const float*)d_in[7];
    const int* s_aa = (const int*)d_in[8];
    const int* d_aa = (const int*)d_in[9];
    const int* s_ab = (const int*)d_in[10];
    const int* d_ab = (const int*)d_in[11];
    const int* s_ba = (const int*)d_in[12];
    const int* d_ba = (const int*)d_in[13];
    const int* s_bb = (const int*)d_in[14];
    const int* d_bb = (const int*)d_in[15];

    const size_t nd = (size_t)N * D;
    char* p = (char*)d_ws;
    ushort* xb = (ushort*)p;                // [2][nd] bf16: layer input; L0 LN writes back
    p += 2 * nd * sizeof(ushort);
    ushort* agg = (ushort*)p;               // [4][nd] bf16 aggregated features
    p += 4 * nd * sizeof(ushort);
    ushort* WF = (ushort*)p;                // [2][4][2048][8] bf16 frag-order
    p += 2 * 4 * 2048 * 8 * sizeof(ushort);
    int* bcnt_s = (int*)p;                  // zeroed zone: 2*4*NBMAX ints
    int* bcnt_d = bcnt_s + 4 * NBMAX;
    int* sbase = bcnt_d + 4 * NBMAX;
    int* scur = sbase + 4 * NBMAX;
    int* dbase = scur + 4 * NBMAX;
    int* dcur = dbase + 4 * NBMAX;
    int* start_g = dcur + 4 * NBMAX;        // [4][N]
    int* cnt_g = start_g + 4 * (size_t)N;   // [4][N]
    p = (char*)(cnt_g + 4 * (size_t)N);
    float* rs_out = (float*)p;
    float* rs_in = rs_out + 4 * (size_t)N;
    p = (char*)(rs_in + 4 * (size_t)N);
    int* csr = (int*)p;                     // [4][E]
    p = (char*)(csr + 4 * (size_t)E);
    ushort* csr_rs = (ushort*)p;            // [4][E] bf16 per-edge weight
    p = (char*)(csr_rs + 4 * (size_t)E);
    // partition scratch aliases agg (agg first written by agg4v2_k, after
    // scatsh_k consumed the partitions).
    uint* part_d = (uint*)agg;              // [4][E] packed (dstLocal<<24 | src)
    uchar* part_s = (uchar*)(part_d + 4 * (size_t)E);  // [4][E] srcLocal u8

    float* hA = (float*)d_out;
    float* hB = hA + nd;

    hipMemsetAsync(bcnt_s, 0, 2 * 4 * NBMAX * sizeof(int), stream);

    const int TB = 256;
    const int NBn = (N + 255) >> BKT_SHIFT;
    const int nd8 = (int)(nd / 8);

    cast2_k<<<(2 * nd8 + 255) / 256, TB, 0, stream>>>(xA, xB, xb, nd8);
    dim3 bhg((E + 8191) / 8192, 4);
    bhist4_k<<<bhg, TB, 0, stream>>>(s_aa, d_aa, s_ab, d_ab, s_ba, d_ba, s_bb, d_bb,
                                     bcnt_s, bcnt_d, N, E);
    dim3 bsg(2, 4);
    bscan_k<<<bsg, 512, 0, stream>>>(bcnt_s, bcnt_d, sbase, scur, dbase, dcur, N);
    dim3 pg4((E + EPB - 1) / EPB, 4);
    part4_k<<<pg4, TB, 0, stream>>>(s_aa, d_aa, s_ab, d_ab, s_ba, d_ba, s_bb, d_bb,
                                    scur, dcur, part_d, part_s, N, E);
    dim3 scg4(NBn, 4);
    scatsh_k<<<scg4, TB, 0, stream>>>(part_d, dbase, bcnt_d, part_s, sbase, bcnt_s,
                                      start_g, cnt_g, rs_in, rs_out, csr, N, E);
    dim3 ewg((E + 1023) / 1024, 4);
    edgew_k<<<ewg, TB, 0, stream>>>(csr, rs_out, csr_rs, N, E);
    wswz_k<<<64, TB, 0, stream>>>(W0, W1, WF);

    dim3 gg(384, 2);
    dim3 ag((N + 3) / 4, 2);
    const size_t WFL = 4 * 2048 * 8;  // ushorts per layer

    // layer 0: aggregate bf16 x, then GEMM+bias+relu+sum+LN -> bf16 back into xb
    agg4v2_k<<<ag, TB, 0, stream>>>(xb, csr, csr_rs, start_g, cnt_g, rs_in, agg, N, E);
    gemm_ln_k<<<gg, TB, 0, stream>>>(agg, WF, b0, lng, lnb, xb, hA, hB, N, 0, 1);
    // layer 1: aggregate h, then GEMM+bias+sum+LN -> f32 d_out
    agg4v2_k<<<ag, TB, 0, stream>>>(xb, csr, csr_rs, start_g, cnt_g, rs_in, agg, N, E);
    gemm_ln_k<<<gg, TB, 0, stream>>>(agg, WF + WFL, b1, lng, lnb, xb, hA, hB, N, 1, 0);
}

// Round 10
// 890.633 us; speedup vs baseline: 1.1365x; 1.1365x over previous
//
#include <hip/hip_runtime.h>
#include <hip/hip_bf16.h>

#define D 128
typedef unsigned int uint;
typedef unsigned short ushort;
typedef unsigned char uchar;
typedef short short8 __attribute__((ext_vector_type(8)));
typedef float f32x4 __attribute__((ext_vector_type(4)));

#define BKT_SHIFT 8           // 256 dst nodes per bucket
#define NBMAX 512             // max buckets per etype (N <= 131072)
#define PART_EPT 16           // edges per thread in part4_k
#define EPB 4096              // edges per block in part4_k (256*PART_EPT)
#define SCAT_CAP 8192         // LDS CSR staging capacity (ints) per bucket

__device__ __forceinline__ ushort f2bf(float f) {
    uint u = __float_as_uint(f);
    return (ushort)((u + 0x7fffu + ((u >> 16) & 1u)) >> 16);
}
__device__ __forceinline__ float bf2f(uint s) { return __uint_as_float(s << 16); }

// ---------------- bucket-granular histogram: LDS privatized ----------------
__global__ __launch_bounds__(256) void bhist4_k(
    const int* __restrict__ s0, const int* __restrict__ d0,
    const int* __restrict__ s1, const int* __restrict__ d1,
    const int* __restrict__ s2, const int* __restrict__ d2,
    const int* __restrict__ s3, const int* __restrict__ d3,
    int* __restrict__ bcs, int* __restrict__ bcd, int N, int E) {
    const int e = blockIdx.y;
    const int* sp = e == 0 ? s0 : e == 1 ? s1 : e == 2 ? s2 : s3;
    const int* dp = e == 0 ? d0 : e == 1 ? d1 : e == 2 ? d2 : d3;
    const int NB = (N + 255) >> BKT_SHIFT;
    __shared__ int hs[NBMAX], hd[NBMAX];
    for (int j = threadIdx.x; j < NBMAX; j += 256) { hs[j] = 0; hd[j] = 0; }
    __syncthreads();
    const int base = blockIdx.x * 8192;
#pragma unroll
    for (int k = 0; k < 8; ++k) {
        int idx = base + (k * 256 + threadIdx.x) * 4;
        if (idx + 4 <= E) {
            int4 s = *(const int4*)(sp + idx);
            int4 d = *(const int4*)(dp + idx);
            atomicAdd(&hs[s.x >> BKT_SHIFT], 1); atomicAdd(&hs[s.y >> BKT_SHIFT], 1);
            atomicAdd(&hs[s.z >> BKT_SHIFT], 1); atomicAdd(&hs[s.w >> BKT_SHIFT], 1);
            atomicAdd(&hd[d.x >> BKT_SHIFT], 1); atomicAdd(&hd[d.y >> BKT_SHIFT], 1);
            atomicAdd(&hd[d.z >> BKT_SHIFT], 1); atomicAdd(&hd[d.w >> BKT_SHIFT], 1);
        } else {
            for (int i = idx; i < E && i < idx + 4; ++i) {
                atomicAdd(&hs[sp[i] >> BKT_SHIFT], 1);
                atomicAdd(&hd[dp[i] >> BKT_SHIFT], 1);
            }
        }
    }
    __syncthreads();
    for (int j = threadIdx.x; j < NB; j += 256) {
        if (hs[j]) atomicAdd(&bcs[e * NBMAX + j], hs[j]);
        if (hd[j]) atomicAdd(&bcd[e * NBMAX + j], hd[j]);
    }
}

// ---------------- exclusive scan over buckets -> bases + cursors ----------------
__global__ __launch_bounds__(512) void bscan_k(
    const int* __restrict__ bcs, const int* __restrict__ bcd,
    int* __restrict__ sbase, int* __restrict__ scur,
    int* __restrict__ dbase, int* __restrict__ dcur, int N) {
    const int e = blockIdx.y;
    const int side = blockIdx.x;
    const int NB = (N + 255) >> BKT_SHIFT;
    const int* in = (side ? bcd : bcs) + e * NBMAX;
    int* b0 = (side ? dbase : sbase) + e * NBMAX;
    int* c0 = (side ? dcur : scur) + e * NBMAX;
    const int tid = threadIdx.x, lane = tid & 63, wid = tid >> 6;
    int v = (tid < NB) ? in[tid] : 0;
    int x = v;
#pragma unroll
    for (int off = 1; off < 64; off <<= 1) {
        int t = __shfl_up(x, off);
        if (lane >= off) x += t;
    }
    __shared__ int ws[8];
    if (lane == 63) ws[wid] = x;
    __syncthreads();
    if (tid == 0) {
        int run = 0;
#pragma unroll
        for (int w = 0; w < 8; ++w) { int t = ws[w]; ws[w] = run; run += t; }
    }
    __syncthreads();
    int excl = ws[wid] + x - v;
    if (tid < NB) { b0[tid] = excl; c0[tid] = excl; }
}

// block-local scan of bucket counts + global range reservation.
__device__ __forceinline__ void scan_reserve(int* h, int* gcur, int* Lb, int* Gb,
                                             int* ws) {
    const int t = threadIdx.x, lane = t & 63, wid = t >> 6;
    int c0 = h[2 * t], c1 = h[2 * t + 1];
    int tsum = c0 + c1;
    int x = tsum;
#pragma unroll
    for (int off = 1; off < 64; off <<= 1) {
        int u = __shfl_up(x, off);
        if (lane >= off) x += u;
    }
    if (lane == 63) ws[wid] = x;
    __syncthreads();
    if (t == 0) {
        int run = 0;
#pragma unroll
        for (int w = 0; w < 4; ++w) { int u = ws[w]; ws[w] = run; run += u; }
    }
    __syncthreads();
    int excl = ws[wid] + x - tsum;
    Lb[2 * t] = excl;
    Lb[2 * t + 1] = excl + c0;
    Gb[2 * t] = c0 ? atomicAdd(&gcur[2 * t], c0) : 0;
    Gb[2 * t + 1] = c1 ? atomicAdd(&gcur[2 * t + 1], c1) : 0;
}

// ---------------- pass 1: bucket-partition with LDS counting-sort ----------------
__global__ __launch_bounds__(256) void part4_k(
    const int* __restrict__ s0, const int* __restrict__ d0,
    const int* __restrict__ s1, const int* __restrict__ d1,
    const int* __restrict__ s2, const int* __restrict__ d2,
    const int* __restrict__ s3, const int* __restrict__ d3,
    int* __restrict__ scur, int* __restrict__ dcur,
    uint* __restrict__ pd, uchar* __restrict__ ps, int N, int E) {
    const int e = blockIdx.y;
    const int* sp = e == 0 ? s0 : e == 1 ? s1 : e == 2 ? s2 : s3;
    const int* dp = e == 0 ? d0 : e == 1 ? d1 : e == 2 ? d2 : d3;
    uint* ptd = pd + (size_t)e * E;
    uchar* pts = ps + (size_t)e * E;
    __shared__ int hd[NBMAX], hs[NBMAX];
    __shared__ int Lb[NBMAX], Gb[NBMAX];
    __shared__ uint rec[EPB];
    __shared__ int dst[EPB];
    __shared__ int ws[4];
    for (int j = threadIdx.x; j < NBMAX; j += 256) { hd[j] = 0; hs[j] = 0; }
    __syncthreads();
    int myd[PART_EPT], mys[PART_EPT], rkd[PART_EPT], rks[PART_EPT];
    const int base = blockIdx.x * EPB;
    const int nE = min(EPB, E - base);
#pragma unroll
    for (int k = 0; k < PART_EPT; ++k) {
        int idx = base + k * 256 + threadIdx.x;
        if (idx < E) {
            int d = dp[idx], s = sp[idx];
            myd[k] = d; mys[k] = s;
            rkd[k] = atomicAdd(&hd[d >> BKT_SHIFT], 1);
            rks[k] = atomicAdd(&hs[s >> BKT_SHIFT], 1);
        } else {
            myd[k] = -1;
        }
    }
    __syncthreads();
    // ---- dst side ----
    scan_reserve(hd, dcur + e * NBMAX, Lb, Gb, ws);
    __syncthreads();
#pragma unroll
    for (int k = 0; k < PART_EPT; ++k) {
        if (myd[k] >= 0) {
            int b = myd[k] >> BKT_SHIFT;
            int q = Lb[b] + rkd[k];
            rec[q] = ((uint)(myd[k] & 255) << 24) | (uint)mys[k];
            dst[q] = Gb[b] + rkd[k];
        }
    }
    __syncthreads();
    for (int i = threadIdx.x; i < nE; i += 256) ptd[dst[i]] = rec[i];
    __syncthreads();
    // ---- src side ----
    scan_reserve(hs, scur + e * NBMAX, Lb, Gb, ws);
    __syncthreads();
#pragma unroll
    for (int k = 0; k < PART_EPT; ++k) {
        if (myd[k] >= 0) {
            int b = mys[k] >> BKT_SHIFT;
            int q = Lb[b] + rks[k];
            rec[q] = (uint)(mys[k] & 255);
            dst[q] = Gb[b] + rks[k];
        }
    }
    __syncthreads();
    for (int i = threadIdx.x; i < nE; i += 256) pts[dst[i]] = (uchar)rec[i];
}

// ---------------- pass 2 (merged): dst scatter -> start/cnt/rs_in/CSR, src count -> rs_out ----------------
__global__ __launch_bounds__(256) void scatsh_k(
    const uint* __restrict__ pd, const int* __restrict__ dbase,
    const int* __restrict__ bcd,
    const uchar* __restrict__ ps, const int* __restrict__ sbase,
    const int* __restrict__ bcs,
    int* __restrict__ start_g, int* __restrict__ cnt_g,
    float* __restrict__ rs_in, float* __restrict__ rs_out,
    int* __restrict__ csr, int N, int E) {
    const int e = blockIdx.y;
    const int b = blockIdx.x;
    const int node0 = b << BKT_SHIFT;
    const int nodes = min(256, N - node0);
    const uint* pt = pd + (size_t)e * E;
    int* out = csr + (size_t)e * E;
    const int csr_base = dbase[e * NBMAX + b];
    const int span = bcd[e * NBMAX + b];
    __shared__ int cnt[256];
    __shared__ int cur[256];
    __shared__ int cs[256];
    __shared__ int woff[4];
    __shared__ int lcsr[SCAT_CAP];
    const int tid = threadIdx.x, lane = tid & 63, wid = tid >> 6;
    cnt[tid] = 0;
    cs[tid] = 0;
    __syncthreads();
    for (int i = tid; i < span; i += 256) atomicAdd(&cnt[pt[csr_base + i] >> 24], 1);
    // src-side count (independent)
    {
        const uchar* pts = ps + (size_t)e * E;
        const int sb = sbase[e * NBMAX + b];
        const int sspan = bcs[e * NBMAX + b];
        for (int i = tid; i < sspan; i += 256) atomicAdd(&cs[pts[sb + i]], 1);
    }
    __syncthreads();
    if (tid < nodes)
        rs_out[(size_t)e * N + node0 + tid] = rsqrtf((float)max(cs[tid], 1));
    int c = cnt[tid];
    int x = c;
#pragma unroll
    for (int off = 1; off < 64; off <<= 1) {
        int t = __shfl_up(x, off);
        if (lane >= off) x += t;
    }
    if (lane == 63) woff[wid] = x;
    __syncthreads();
    if (tid == 0) {
        int run = 0;
#pragma unroll
        for (int w = 0; w < 4; ++w) { int t = woff[w]; woff[w] = run; run += t; }
    }
    __syncthreads();
    int loc = woff[wid] + x - c;
    cur[tid] = loc;
    if (tid < nodes) {
        int n = node0 + tid;
        start_g[(size_t)e * N + n] = csr_base + loc;
        cnt_g[(size_t)e * N + n] = c;
        rs_in[(size_t)e * N + n] = rsqrtf((float)max(c, 1));
    }
    __syncthreads();
    for (int i = tid; i < span; i += 256) {
        uint pk = pt[csr_base + i];
        int pos = atomicAdd(&cur[pk >> 24], 1);
        int s = (int)(pk & 0xFFFFFFu);
        if (pos < SCAT_CAP) lcsr[pos] = s;
        else out[csr_base + pos] = s;  // paranoia guard; statistically unreachable
    }
    __syncthreads();
    const int lim = span < SCAT_CAP ? span : SCAT_CAP;
    for (int i = tid; i < lim; i += 256) out[csr_base + i] = lcsr[i];
}

// ---------------- W pre-swizzle into MFMA A-operand (W^T) frag order ----------------
__global__ __launch_bounds__(256) void wswz_k(const float* __restrict__ W0,
                                              const float* __restrict__ W1,
                                              ushort* __restrict__ WF) {
    int t = blockIdx.x * 256 + threadIdx.x;  // 16384 threads total
    int lane = t & 63, kf = (t >> 6) & 3, ct = (t >> 8) & 7, e = (t >> 11) & 3, l = (t >> 13) & 1;
    const float* Ws = (l ? W1 : W0) + (size_t)e * D * D;
    int m = lane & 15, q = lane >> 4;
    const float* src = Ws + (size_t)(kf * 32 + q * 8) * D + ct * 16 + m;
    ushort v[8];
#pragma unroll
    for (int j = 0; j < 8; ++j) v[j] = f2bf(src[(size_t)j * D]);
    uint4 pk;
    pk.x = (uint)v[0] | ((uint)v[1] << 16);
    pk.y = (uint)v[2] | ((uint)v[3] << 16);
    pk.z = (uint)v[4] | ((uint)v[5] << 16);
    pk.w = (uint)v[6] | ((uint)v[7] << 16);
    *(uint4*)(WF + ((size_t)(l * 4 + e) * 2048 + (ct * 4 + kf) * 64 + lane) * 8) = pk;
}

// ---------------- pair-fused MFMA GEMM: y[e] = bf16((X@W_e)*rs_e) for e=2p,2p+1 ----------------
// Input either f32 (XAf/XBf, layer 0) or bf16 (Xb = [2][n*D], layer 1).
__global__ __launch_bounds__(256) void gemm_pair_k(
    const float* __restrict__ XAf, const float* __restrict__ XBf,
    const ushort* __restrict__ Xb, int bf16in,
    const ushort* __restrict__ WF,  // layer base: [4][2048][8] bf16
    const float* __restrict__ rs,   // [4][n]
    ushort* __restrict__ yb,        // [4][n*D]
    int n) {
    const int p = blockIdx.y;
    const float* Xf = p ? XBf : XAf;
    const ushort* Xh = Xb + (size_t)p * n * D;
    const int e0 = 2 * p, e1 = 2 * p + 1;
    const short8* F0 = (const short8*)(WF + (size_t)e0 * 16384);
    const short8* F1 = (const short8*)(WF + (size_t)e1 * 16384);
    const float* rs0 = rs + (size_t)e0 * n;
    const float* rs1 = rs + (size_t)e1 * n;
    ushort* Y0 = yb + (size_t)e0 * n * D;
    ushort* Y1 = yb + (size_t)e1 * n * D;
    const int lane = threadIdx.x & 63;
    const int m = lane & 15, q = lane >> 4;
    const int wave = blockIdx.x * 4 + (threadIdx.x >> 6);
    const int nw = gridDim.x * 4;
    const int nstrips = (n + 15) >> 4;
    for (int sidx = wave; sidx < nstrips; sidx += nw) {
        const int r = sidx * 16 + m;
        const int rc = r < n ? r : n - 1;
        short8 xf[4];
        if (bf16in) {
            const ushort* xp = Xh + (size_t)rc * D + q * 8;
#pragma unroll
            for (int kf = 0; kf < 4; ++kf) xf[kf] = *(const short8*)(xp + kf * 32);
        } else {
            const float* xp = Xf + (size_t)rc * D + q * 8;
#pragma unroll
            for (int kf = 0; kf < 4; ++kf) {
                float4 u0 = *(const float4*)(xp + kf * 32);
                float4 u1 = *(const float4*)(xp + kf * 32 + 4);
                short8 v;
                v[0] = (short)f2bf(u0.x); v[1] = (short)f2bf(u0.y);
                v[2] = (short)f2bf(u0.z); v[3] = (short)f2bf(u0.w);
                v[4] = (short)f2bf(u1.x); v[5] = (short)f2bf(u1.y);
                v[6] = (short)f2bf(u1.z); v[7] = (short)f2bf(u1.w);
                xf[kf] = v;
            }
        }
        f32x4 a0[8], a1[8];
#pragma unroll
        for (int ct = 0; ct < 8; ++ct) {
            a0[ct] = (f32x4){0.f, 0.f, 0.f, 0.f};
            a1[ct] = (f32x4){0.f, 0.f, 0.f, 0.f};
        }
#pragma unroll
        for (int ct = 0; ct < 8; ++ct)
#pragma unroll
            for (int kf = 0; kf < 4; ++kf) {
                a0[ct] = __builtin_amdgcn_mfma_f32_16x16x32_bf16(
                    F0[(ct * 4 + kf) * 64 + lane], xf[kf], a0[ct], 0, 0, 0);
                a1[ct] = __builtin_amdgcn_mfma_f32_16x16x32_bf16(
                    F1[(ct * 4 + kf) * 64 + lane], xf[kf], a1[ct], 0, 0, 0);
            }
        if (r < n) {
            float s0v = rs0[r], s1v = rs1[r];
            ushort* y0r = Y0 + (size_t)r * D + q * 4;
            ushort* y1r = Y1 + (size_t)r * D + q * 4;
#pragma unroll
            for (int ct = 0; ct < 8; ++ct) {
                uint2 w;
                w.x = (uint)f2bf(a0[ct][0] * s0v) | ((uint)f2bf(a0[ct][1] * s0v) << 16);
                w.y = (uint)f2bf(a0[ct][2] * s0v) | ((uint)f2bf(a0[ct][3] * s0v) << 16);
                *(uint2*)(y0r + ct * 16) = w;
                uint2 z;
                z.x = (uint)f2bf(a1[ct][0] * s1v) | ((uint)f2bf(a1[ct][1] * s1v) << 16);
                z.y = (uint)f2bf(a1[ct][2] * s1v) | ((uint)f2bf(a1[ct][3] * s1v) << 16);
                *(uint2*)(y1r + ct * 16) = z;
            }
        }
    }
}

// ---------------- fused dual-relation aggregation + bias + relu + LayerNorm ----------------
// blockIdx.y = dst ntype; 1 wave/row, 2 cols/lane. Output bf16 (layer0) or f32 (layer1).
__global__ __launch_bounds__(256) void agg_ln2_k(
    const ushort* __restrict__ yb, const int* __restrict__ csr,
    const int* __restrict__ start, const int* __restrict__ cnt,
    const float* __restrict__ rs_in, const float* __restrict__ bias,
    const float* __restrict__ lng, const float* __restrict__ lnb,
    ushort* __restrict__ hb, float* __restrict__ outA, float* __restrict__ outB,
    int N, int E, int act, int layer, int outbf) {
    const int dt = blockIdx.y;
    const int eA = dt, eB = dt + 2;
    const int lane = threadIdx.x & 63;
    const int row = blockIdx.x * 4 + (threadIdx.x >> 6);
    if (row >= N) return;
    const uint* YuA = (const uint*)(yb + (size_t)eA * N * D);
    const uint* YuB = (const uint*)(yb + (size_t)eB * N * D);
    const int* cAp = csr + (size_t)eA * E;
    const int* cBp = csr + (size_t)eB * E;
    int iA = start[(size_t)eA * N + row], enA = iA + cnt[(size_t)eA * N + row];
    int iB = start[(size_t)eB * N + row], enB = iB + cnt[(size_t)eB * N + row];
    float a0 = 0.f, a1 = 0.f, c0 = 0.f, c1 = 0.f;
    while (iA + 4 <= enA && iB + 4 <= enB) {
        int sa0 = cAp[iA], sa1 = cAp[iA + 1], sa2 = cAp[iA + 2], sa3 = cAp[iA + 3];
        int sb0 = cBp[iB], sb1 = cBp[iB + 1], sb2 = cBp[iB + 2], sb3 = cBp[iB + 3];
        uint pa0 = YuA[(size_t)sa0 * 64 + lane], pa1 = YuA[(size_t)sa1 * 64 + lane];
        uint pa2 = YuA[(size_t)sa2 * 64 + lane], pa3 = YuA[(size_t)sa3 * 64 + lane];
        uint pb0 = YuB[(size_t)sb0 * 64 + lane], pb1 = YuB[(size_t)sb1 * 64 + lane];
        uint pb2 = YuB[(size_t)sb2 * 64 + lane], pb3 = YuB[(size_t)sb3 * 64 + lane];
        a0 += bf2f(pa0 & 0xffffu) + bf2f(pa1 & 0xffffu) + bf2f(pa2 & 0xffffu) + bf2f(pa3 & 0xffffu);
        a1 += bf2f(pa0 >> 16) + bf2f(pa1 >> 16) + bf2f(pa2 >> 16) + bf2f(pa3 >> 16);
        c0 += bf2f(pb0 & 0xffffu) + bf2f(pb1 & 0xffffu) + bf2f(pb2 & 0xffffu) + bf2f(pb3 & 0xffffu);
        c1 += bf2f(pb0 >> 16) + bf2f(pb1 >> 16) + bf2f(pb2 >> 16) + bf2f(pb3 >> 16);
        iA += 4; iB += 4;
    }
    for (; iA + 4 <= enA; iA += 4) {
        int s0 = cAp[iA], s1 = cAp[iA + 1], s2 = cAp[iA + 2], s3 = cAp[iA + 3];
        uint p0 = YuA[(size_t)s0 * 64 + lane], p1 = YuA[(size_t)s1 * 64 + lane];
        uint p2 = YuA[(size_t)s2 * 64 + lane], p3 = YuA[(size_t)s3 * 64 + lane];
        a0 += bf2f(p0 & 0xffffu) + bf2f(p1 & 0xffffu) + bf2f(p2 & 0xffffu) + bf2f(p3 & 0xffffu);
        a1 += bf2f(p0 >> 16) + bf2f(p1 >> 16) + bf2f(p2 >> 16) + bf2f(p3 >> 16);
    }
    for (; iB + 4 <= enB; iB += 4) {
        int s0 = cBp[iB], s1 = cBp[iB + 1], s2 = cBp[iB + 2], s3 = cBp[iB + 3];
        uint p0 = YuB[(size_t)s0 * 64 + lane], p1 = YuB[(size_t)s1 * 64 + lane];
        uint p2 = YuB[(size_t)s2 * 64 + lane], p3 = YuB[(size_t)s3 * 64 + lane];
        c0 += bf2f(p0 & 0xffffu) + bf2f(p1 & 0xffffu) + bf2f(p2 & 0xffffu) + bf2f(p3 & 0xffffu);
        c1 += bf2f(p0 >> 16) + bf2f(p1 >> 16) + bf2f(p2 >> 16) + bf2f(p3 >> 16);
    }
    for (; iA < enA; ++iA) {
        uint p = YuA[(size_t)cAp[iA] * 64 + lane];
        a0 += bf2f(p & 0xffffu); a1 += bf2f(p >> 16);
    }
    for (; iB < enB; ++iB) {
        uint p = YuB[(size_t)cBp[iB] * 64 + lane];
        c0 += bf2f(p & 0xffffu); c1 += bf2f(p >> 16);
    }
    float riA = rs_in[(size_t)eA * N + row], riB = rs_in[(size_t)eB * N + row];
    float2 bA = *(const float2*)(bias + eA * D + lane * 2);
    float2 bB = *(const float2*)(bias + eB * D + lane * 2);
    float v0 = fmaf(a0, riA, bA.x), v1 = fmaf(a1, riA, bA.y);
    float w0 = fmaf(c0, riB, bB.x), w1 = fmaf(c1, riB, bB.y);
    if (act) {
        v0 = fmaxf(v0, 0.f); v1 = fmaxf(v1, 0.f);
        w0 = fmaxf(w0, 0.f); w1 = fmaxf(w1, 0.f);
    }
    v0 += w0; v1 += w1;
    float s = v0 + v1, qq = v0 * v0 + v1 * v1;
#pragma unroll
    for (int off = 1; off < 64; off <<= 1) {
        s += __shfl_xor(s, off);
        qq += __shfl_xor(qq, off);
    }
    float mean = s * (1.f / 128.f);
    float var = qq * (1.f / 128.f) - mean * mean;
    float inv = rsqrtf(var + 1e-5f);
    const int gi = (layer * 2 + dt) * D + lane * 2;
    float2 g = *(const float2*)(lng + gi);
    float2 be = *(const float2*)(lnb + gi);
    float o0 = fmaf((v0 - mean) * inv, g.x, be.x);
    float o1 = fmaf((v1 - mean) * inv, g.y, be.y);
    if (outbf) {
        uint* H = (uint*)(hb + (size_t)dt * N * D);
        H[(size_t)row * 64 + lane] = (uint)f2bf(o0) | ((uint)f2bf(o1) << 16);
    } else {
        float* OUT = dt ? outB : outA;
        float2 o; o.x = o0; o.y = o1;
        *(float2*)(OUT + (size_t)row * D + lane * 2) = o;
    }
}

extern "C" void kernel_launch(void* const* d_in, const int* in_sizes, int n_in,
                              void* d_out, int out_size, void* d_ws, size_t ws_size,
                              hipStream_t stream) {
    const int N = in_sizes[0] / D;
    const int E = in_sizes[8];
    const float* xA = (const float*)d_in[0];
    const float* xB = (const float*)d_in[1];
    const float* W0 = (const float*)d_in[2];
    const float* b0 = (const float*)d_in[3];
    const float* W1 = (const float*)d_in[4];
    const float* b1 = (const float*)d_in[5];
    const float* lng = (const float*)d_in[6];
    const float* lnb = (const float*)d_in[7];
    const int* s_aa = (const int*)d_in[8];
    const int* d_aa = (const int*)d_in[9];
    const int* s_ab = (const int*)d_in[10];
    const int* d_ab = (const int*)d_in[11];
    const int* s_ba = (const int*)d_in[12];
    const int* d_ba = (const int*)d_in[13];
    const int* s_bb = (const int*)d_in[14];
    const int* d_bb = (const int*)d_in[15];

    const size_t nd = (size_t)N * D;
    char* p = (char*)d_ws;
    ushort* y = (ushort*)p;                 // [4][N*D] bf16 per-etype GEMM out
    p += 4 * nd * sizeof(ushort);
    ushort* hb = (ushort*)p;                // [2][N*D] bf16 layer-0 LN output
    p += 2 * nd * sizeof(ushort);
    ushort* WF = (ushort*)p;                // [2][4][2048][8] bf16 frag-order
    p += 2 * 4 * 2048 * 8 * sizeof(ushort);
    int* bcnt_s = (int*)p;                  // zeroed zone: 2*4*NBMAX ints
    int* bcnt_d = bcnt_s + 4 * NBMAX;
    int* sbase = bcnt_d + 4 * NBMAX;
    int* scur = sbase + 4 * NBMAX;
    int* dbase = scur + 4 * NBMAX;
    int* dcur = dbase + 4 * NBMAX;
    int* start_g = dcur + 4 * NBMAX;        // [4][N]
    int* cnt_g = start_g + 4 * (size_t)N;   // [4][N]
    p = (char*)(cnt_g + 4 * (size_t)N);
    float* rs_out = (float*)p;
    float* rs_in = rs_out + 4 * (size_t)N;
    p = (char*)(rs_in + 4 * (size_t)N);
    int* csr = (int*)p;                     // [4][E]
    // partition scratch aliases y (y first written by gemm_pair_k, which is
    // stream-ordered after scatsh_k consumes the partitions).
    uint* part_d = (uint*)y;                // [4][E] packed (dstLocal<<24 | src)
    uchar* part_s = (uchar*)(part_d + 4 * (size_t)E);  // [4][E] srcLocal u8

    float* hA = (float*)d_out;
    float* hB = hA + nd;

    hipMemsetAsync(bcnt_s, 0, 2 * 4 * NBMAX * sizeof(int), stream);

    const int TB = 256;
    const int NBn = (N + 255) >> BKT_SHIFT;

    dim3 bhg((E + 8191) / 8192, 4);
    bhist4_k<<<bhg, TB, 0, stream>>>(s_aa, d_aa, s_ab, d_ab, s_ba, d_ba, s_bb, d_bb,
                                     bcnt_s, bcnt_d, N, E);
    dim3 bsg(2, 4);
    bscan_k<<<bsg, 512, 0, stream>>>(bcnt_s, bcnt_d, sbase, scur, dbase, dcur, N);
    dim3 pg4((E + EPB - 1) / EPB, 4);
    part4_k<<<pg4, TB, 0, stream>>>(s_aa, d_aa, s_ab, d_ab, s_ba, d_ba, s_bb, d_bb,
                                    scur, dcur, part_d, part_s, N, E);
    dim3 scg4(NBn, 4);
    scatsh_k<<<scg4, TB, 0, stream>>>(part_d, dbase, bcnt_d, part_s, sbase, bcnt_s,
                                      start_g, cnt_g, rs_in, rs_out, csr, N, E);
    wswz_k<<<64, TB, 0, stream>>>(W0, W1, WF);

    dim3 gg(384, 2);
    dim3 ag((N + 3) / 4, 2);
    const size_t WFL = 4 * 2048 * 8;  // ushorts per layer

    // layer 0: f32 input -> y, then agg+LN -> bf16 hb
    gemm_pair_k<<<gg, TB, 0, stream>>>(xA, xB, hb, 0, WF, rs_out, y, N);
    agg_ln2_k<<<ag, TB, 0, stream>>>(y, csr, start_g, cnt_g, rs_in, b0,
                                     lng, lnb, hb, hA, hB, N, E, 1, 0, 1);
    // layer 1: bf16 hb input -> y, then agg+LN -> f32 out
    gemm_pair_k<<<gg, TB, 0, stream>>>(xA, xB, hb, 1, WF + WFL, rs_out, y, N);
    agg_ln2_k<<<ag, TB, 0, stream>>>(y, csr, start_g, cnt_g, rs_in, b1,
                                     lng, lnb, hb, hA, hB, N, E, 0, 1, 0);
}